// Round 1
// baseline (1264.443 us; speedup 1.0000x reference)
//
#include <hip/hip_runtime.h>
#include <math.h>

// GAT, N=4096 nodes, ~1% dense adjacency (~41 nbrs/row).
// Pipeline: CSR build -> per-layer [batched SGEMM -> f1/f2 -> sparse softmax-aggregate].
// All fp32 this round (no fp32 MFMA on CDNA4 -> vector ALU GEMM).

#define N_NODES 4096
#define MAXNB 128   // max degree: Binomial(4096,0.01) max ~65; 128 is safe

// ---------------- reduction helpers (blockDim == 256) ----------------
__device__ __forceinline__ float wave_sum(float v) {
#pragma unroll
  for (int o = 32; o > 0; o >>= 1) v += __shfl_xor(v, o);
  return v;
}
__device__ __forceinline__ float wave_max(float v) {
#pragma unroll
  for (int o = 32; o > 0; o >>= 1) v = fmaxf(v, __shfl_xor(v, o));
  return v;
}
__device__ __forceinline__ float block_sum(float v, float* buf) {
  v = wave_sum(v);
  __syncthreads();
  if ((threadIdx.x & 63) == 0) buf[threadIdx.x >> 6] = v;
  __syncthreads();
  return buf[0] + buf[1] + buf[2] + buf[3];
}
__device__ __forceinline__ float block_max(float v, float* buf) {
  v = wave_max(v);
  __syncthreads();
  if ((threadIdx.x & 63) == 0) buf[threadIdx.x >> 6] = v;
  __syncthreads();
  return fmaxf(fmaxf(buf[0], buf[1]), fmaxf(buf[2], buf[3]));
}

// ---------------- CSR build: one block per row ----------------
__global__ __launch_bounds__(256) void build_csr(const float* __restrict__ adj,
                                                 int* __restrict__ cnt,
                                                 int* __restrict__ idx) {
  __shared__ int c;
  if (threadIdx.x == 0) c = 0;
  __syncthreads();
  const int row = blockIdx.x;
  const float* arow = adj + (size_t)row * N_NODES;
  for (int b = 0; b < N_NODES; b += 256) {
    float v = arow[b + threadIdx.x];
    if (v > 0.f) {
      int p = atomicAdd(&c, 1);
      if (p < MAXNB) idx[row * MAXNB + p] = b + threadIdx.x;
    }
  }
  __syncthreads();
  if (threadIdx.x == 0) cnt[row] = c < MAXNB ? c : MAXNB;
}

// ---------------- batched fp32 GEMM: C[h] = A @ B[h] ----------------
// A: [N_NODES, K] (shared over heads), B: [H, K, D], C: [H, N_NODES, D]
// 128x128 tile, BK=16, 256 threads, 8x8 per thread.
__global__ __launch_bounds__(256) void gemm_heads(const float* __restrict__ A,
                                                  const float* __restrict__ B,
                                                  float* __restrict__ C,
                                                  int K, int D) {
  const int h = blockIdx.z;
  const float* Bh = B + (size_t)h * K * D;
  float* Ch = C + (size_t)h * N_NODES * D;
  const int m0 = blockIdx.x * 128;
  const int n0 = blockIdx.y * 128;

  __shared__ float As[16][128];  // k-major for contiguous fragment reads
  __shared__ float Bs[16][128];

  const int tid = threadIdx.x;
  const int tr = tid & 15, tc = tid >> 4;
  const int lrow = tid >> 2;          // 0..63  (A tile row)
  const int lk = (tid & 3) << 2;      // 0,4,8,12 (A tile k quad)
  const int bk = tid >> 5;            // 0..7   (B tile k row)
  const int bn = (tid & 31) << 2;     // 0..124 (B tile col quad)

  float acc[8][8];
#pragma unroll
  for (int i = 0; i < 8; i++)
#pragma unroll
    for (int j = 0; j < 8; j++) acc[i][j] = 0.f;

  for (int k0 = 0; k0 < K; k0 += 16) {
    float4 av0 = *(const float4*)(A + (size_t)(m0 + lrow) * K + k0 + lk);
    float4 av1 = *(const float4*)(A + (size_t)(m0 + lrow + 64) * K + k0 + lk);
    float4 bv0 = *(const float4*)(Bh + (size_t)(k0 + bk) * D + n0 + bn);
    float4 bv1 = *(const float4*)(Bh + (size_t)(k0 + bk + 8) * D + n0 + bn);
    __syncthreads();  // previous iteration's reads done before overwrite
    As[lk + 0][lrow] = av0.x; As[lk + 1][lrow] = av0.y;
    As[lk + 2][lrow] = av0.z; As[lk + 3][lrow] = av0.w;
    As[lk + 0][lrow + 64] = av1.x; As[lk + 1][lrow + 64] = av1.y;
    As[lk + 2][lrow + 64] = av1.z; As[lk + 3][lrow + 64] = av1.w;
    *(float4*)&Bs[bk][bn] = bv0;
    *(float4*)&Bs[bk + 8][bn] = bv1;
    __syncthreads();
#pragma unroll
    for (int k = 0; k < 16; k++) {
      float4 a0 = *(const float4*)&As[k][tr * 8];
      float4 a1 = *(const float4*)&As[k][tr * 8 + 4];
      float4 b0 = *(const float4*)&Bs[k][tc * 8];
      float4 b1 = *(const float4*)&Bs[k][tc * 8 + 4];
      float ar[8] = {a0.x, a0.y, a0.z, a0.w, a1.x, a1.y, a1.z, a1.w};
      float br[8] = {b0.x, b0.y, b0.z, b0.w, b1.x, b1.y, b1.z, b1.w};
#pragma unroll
      for (int i = 0; i < 8; i++)
#pragma unroll
        for (int j = 0; j < 8; j++) acc[i][j] = fmaf(ar[i], br[j], acc[i][j]);
    }
  }
#pragma unroll
  for (int i = 0; i < 8; i++) {
    float* crow = Ch + (size_t)(m0 + tr * 8 + i) * D + n0 + tc * 8;
#pragma unroll
    for (int j = 0; j < 8; j += 4)
      *(float4*)(crow + j) =
          make_float4(acc[i][j], acc[i][j + 1], acc[i][j + 2], acc[i][j + 3]);
  }
}

// ---------------- f1/f2: per-node dot of Wh rows with a-halves ----------------
__global__ __launch_bounds__(256) void fvec(const float* __restrict__ Wh,
                                            const float* __restrict__ a,
                                            float* __restrict__ f1,
                                            float* __restrict__ f2, int H, int Dd) {
  __shared__ float buf[4];
  const int n = blockIdx.x;
  for (int h = 0; h < H; h++) {
    float s1 = 0.f, s2 = 0.f;
    for (int d = threadIdx.x; d < Dd; d += 256) {
      float v = Wh[((size_t)h * N_NODES + n) * Dd + d];
      s1 += v * a[(size_t)h * 2 * Dd + d];
      s2 += v * a[(size_t)h * 2 * Dd + Dd + d];
    }
    float t1 = block_sum(s1, buf);
    float t2 = block_sum(s2, buf);
    if (threadIdx.x == 0) {
      f1[h * N_NODES + n] = t1;
      f2[h * N_NODES + n] = t2;
    }
  }
}

// ---------------- layers 1&2: sparse softmax-aggregate + elu(elu(.)) ----------------
// D=256 fixed; out layout [n][h*256+d] (matches transpose+reshape concat).
__global__ __launch_bounds__(256) void agg_concat(const float* __restrict__ Wh,
                                                  const float* __restrict__ f1,
                                                  const float* __restrict__ f2,
                                                  const int* __restrict__ cnt,
                                                  const int* __restrict__ idxs,
                                                  float* __restrict__ hout, int H) {
  __shared__ int nbs[MAXNB];
  __shared__ float w[MAXNB];
  __shared__ float buf[4];
  const int n = blockIdx.x, tid = threadIdx.x;
  const int c = cnt[n];
  if (tid < c) nbs[tid] = idxs[n * MAXNB + tid];
  __syncthreads();
  for (int h = 0; h < H; h++) {
    float e = -3.0e38f;
    if (tid < c) {
      float s = f1[h * N_NODES + n] + f2[h * N_NODES + nbs[tid]];
      e = s >= 0.f ? s : 0.2f * s;  // leaky_relu, alpha=0.2
    }
    float m = block_max(e, buf);
    float wj = (tid < c) ? __expf(e - m) : 0.f;
    float tot = block_sum(wj, buf);
    if (tid < c) w[tid] = wj / tot;  // masked entries: exp underflows to 0 exactly
    __syncthreads();
    float acc = 0.f;
    for (int jj = 0; jj < c; jj++)
      acc += w[jj] * Wh[((size_t)h * N_NODES + nbs[jj]) * 256 + tid];
    float v = acc;
    v = v > 0.f ? v : __expf(v) - 1.f;  // elu (per-head)
    v = v > 0.f ? v : __expf(v) - 1.f;  // elu (post-concat)
    hout[(size_t)n * 1024 + h * 256 + tid] = v;
    __syncthreads();  // protect w before next head rewrites it
  }
}

// ---------------- layer 3: aggregate 6 heads, mean, elu, L2-normalize ----------------
// D=512: each thread owns components tid and tid+256.
__global__ __launch_bounds__(256) void final_layer(const float* __restrict__ Wh,
                                                   const float* __restrict__ f1,
                                                   const float* __restrict__ f2,
                                                   const int* __restrict__ cnt,
                                                   const int* __restrict__ idxs,
                                                   float* __restrict__ out) {
  __shared__ int nbs[MAXNB];
  __shared__ float w[MAXNB];
  __shared__ float buf[4];
  const int n = blockIdx.x, tid = threadIdx.x;
  const int c = cnt[n];
  if (tid < c) nbs[tid] = idxs[n * MAXNB + tid];
  __syncthreads();
  float a0 = 0.f, a1 = 0.f;
  for (int h = 0; h < 6; h++) {
    float e = -3.0e38f;
    if (tid < c) {
      float s = f1[h * N_NODES + n] + f2[h * N_NODES + nbs[tid]];
      e = s >= 0.f ? s : 0.2f * s;
    }
    float m = block_max(e, buf);
    float wj = (tid < c) ? __expf(e - m) : 0.f;
    float tot = block_sum(wj, buf);
    if (tid < c) w[tid] = wj / tot;
    __syncthreads();
    for (int jj = 0; jj < c; jj++) {
      const float* row = Wh + ((size_t)h * N_NODES + nbs[jj]) * 512;
      a0 += w[jj] * row[tid];
      a1 += w[jj] * row[tid + 256];
    }
    __syncthreads();
  }
  a0 *= (1.f / 6.f);
  a1 *= (1.f / 6.f);
  a0 = a0 > 0.f ? a0 : __expf(a0) - 1.f;
  a1 = a1 > 0.f ? a1 : __expf(a1) - 1.f;
  float ss = block_sum(a0 * a0 + a1 * a1, buf);
  float inv = 1.f / fmaxf(sqrtf(ss), 1e-12f);
  out[(size_t)n * 512 + tid] = a0 * inv;
  out[(size_t)n * 512 + 256 + tid] = a1 * inv;
}

extern "C" void kernel_launch(void* const* d_in, const int* in_sizes, int n_in,
                              void* d_out, int out_size, void* d_ws, size_t ws_size,
                              hipStream_t stream) {
  (void)in_sizes; (void)n_in; (void)out_size; (void)ws_size;
  const float* x   = (const float*)d_in[0];  // [4096, 2048]
  const float* adj = (const float*)d_in[1];  // [4096, 4096]
  const float* W1  = (const float*)d_in[2];  // [4, 2048, 256]
  const float* a1  = (const float*)d_in[3];  // [4, 512]
  const float* W2  = (const float*)d_in[4];  // [4, 1024, 256]
  const float* a2  = (const float*)d_in[5];  // [4, 512]
  const float* W3  = (const float*)d_in[6];  // [6, 1024, 512]
  const float* a3  = (const float*)d_in[7];  // [6, 1024]
  float* out = (float*)d_out;                // [4096, 512]

  // workspace layout (~69.4 MB total)
  char* ws = (char*)d_ws;
  size_t off = 0;
  int* nbr_cnt = (int*)(ws + off); off += (size_t)N_NODES * 4;                 // 16 KB
  int* nbr_idx = (int*)(ws + off); off += (size_t)N_NODES * MAXNB * 4;         // 2 MB
  float* Wh = (float*)(ws + off);  off += (size_t)6 * N_NODES * 512 * 4;       // 50.3 MB (max: layer 3)
  float* f1 = (float*)(ws + off);  off += (size_t)6 * N_NODES * 4;
  float* f2 = (float*)(ws + off);  off += (size_t)6 * N_NODES * 4;
  float* h1 = (float*)(ws + off);  off += (size_t)N_NODES * 1024 * 4;          // 16.8 MB (reused L1 out / L2 out)

  build_csr<<<N_NODES, 256, 0, stream>>>(adj, nbr_cnt, nbr_idx);

  // layer 1: x[4096,2048] @ W1 -> Wh[4,4096,256]
  gemm_heads<<<dim3(32, 2, 4), 256, 0, stream>>>(x, W1, Wh, 2048, 256);
  fvec<<<N_NODES, 256, 0, stream>>>(Wh, a1, f1, f2, 4, 256);
  agg_concat<<<N_NODES, 256, 0, stream>>>(Wh, f1, f2, nbr_cnt, nbr_idx, h1, 4);

  // layer 2: h1[4096,1024] @ W2 -> Wh[4,4096,256]   (h1 dead after GEMM -> reuse as L2 output)
  gemm_heads<<<dim3(32, 2, 4), 256, 0, stream>>>(h1, W2, Wh, 1024, 256);
  fvec<<<N_NODES, 256, 0, stream>>>(Wh, a2, f1, f2, 4, 256);
  agg_concat<<<N_NODES, 256, 0, stream>>>(Wh, f1, f2, nbr_cnt, nbr_idx, h1, 4);

  // layer 3: h1[4096,1024] @ W3 -> Wh[6,4096,512]; aggregate+mean+elu+normalize -> out
  gemm_heads<<<dim3(32, 4, 6), 256, 0, stream>>>(h1, W3, Wh, 1024, 512);
  fvec<<<N_NODES, 256, 0, stream>>>(Wh, a3, f1, f2, 6, 512);
  final_layer<<<N_NODES, 256, 0, stream>>>(Wh, f1, f2, nbr_cnt, nbr_idx, out);
}

// Round 3
// 786.229 us; speedup vs baseline: 1.6082x; 1.6082x over previous
//
#include <hip/hip_runtime.h>
#include <math.h>

// GAT, N=4096, ~1% adjacency. R3: split-bf16 MFMA GEMMs (Ah@Bh + Ah@Bl + Al@Bh).
// Fix vs R2: 16x16x32 MFMA consumes all 32 k per call (lane k = quad*8+j) ->
// exactly ONE mfma-triple per (i,j) per BK=32 tile (R2's kk-loop read OOB chunks).
// LDS tiles linear k-major (no swizzle). Wh layout: [n][h*D+d].

#define N_NODES 4096
#define MAXNB 128
#define BM 128
#define BN 64
#define BK 32

typedef short bf16x8 __attribute__((ext_vector_type(8)));
typedef float f32x4 __attribute__((ext_vector_type(4)));

#define GLL(gp, lp)                                                     \
  __builtin_amdgcn_global_load_lds(                                     \
      (const __attribute__((address_space(1))) void*)(gp),              \
      (__attribute__((address_space(3))) void*)(lp), 16, 0, 0)

// ---------------- bf16 split helpers ----------------
__device__ __forceinline__ unsigned short bf16_rne(float f) {
  unsigned int u = __float_as_uint(f);
  unsigned int r = (u + 0x7FFFu + ((u >> 16) & 1u)) >> 16;
  return (unsigned short)r;
}
__device__ __forceinline__ void split_bf16(float f, unsigned short& h,
                                           unsigned short& l) {
  h = bf16_rne(f);
  float fh = __uint_as_float((unsigned int)h << 16);
  l = bf16_rne(f - fh);
}

// ---------------- reduction helpers (blockDim == 256) ----------------
__device__ __forceinline__ float wave_sum(float v) {
#pragma unroll
  for (int o = 32; o > 0; o >>= 1) v += __shfl_xor(v, o);
  return v;
}
__device__ __forceinline__ float wave_max(float v) {
#pragma unroll
  for (int o = 32; o > 0; o >>= 1) v = fmaxf(v, __shfl_xor(v, o));
  return v;
}
__device__ __forceinline__ float block_sum(float v, float* buf) {
  v = wave_sum(v);
  __syncthreads();
  if ((threadIdx.x & 63) == 0) buf[threadIdx.x >> 6] = v;
  __syncthreads();
  return buf[0] + buf[1] + buf[2] + buf[3];
}
__device__ __forceinline__ float block_max(float v, float* buf) {
  v = wave_max(v);
  __syncthreads();
  if ((threadIdx.x & 63) == 0) buf[threadIdx.x >> 6] = v;
  __syncthreads();
  return fmaxf(fmaxf(buf[0], buf[1]), fmaxf(buf[2], buf[3]));
}

// ---------------- CSR build ----------------
__global__ __launch_bounds__(256) void build_csr(const float* __restrict__ adj,
                                                 int* __restrict__ cnt,
                                                 int* __restrict__ idx) {
  __shared__ int c;
  if (threadIdx.x == 0) c = 0;
  __syncthreads();
  const int row = blockIdx.x;
  const float* arow = adj + (size_t)row * N_NODES;
  for (int b = 0; b < N_NODES; b += 256) {
    float v = arow[b + threadIdx.x];
    if (v > 0.f) {
      int p = atomicAdd(&c, 1);
      if (p < MAXNB) idx[row * MAXNB + p] = b + threadIdx.x;
    }
  }
  __syncthreads();
  if (threadIdx.x == 0) cnt[row] = c < MAXNB ? c : MAXNB;
}

// ---------------- elementwise fp32 -> bf16 hi/lo ----------------
__global__ __launch_bounds__(256) void convert_split(const float* __restrict__ in,
                                                     unsigned short* __restrict__ oh,
                                                     unsigned short* __restrict__ ol,
                                                     int n4) {
  int i = blockIdx.x * 256 + threadIdx.x;
  if (i >= n4) return;
  float4 v = ((const float4*)in)[i];
  ushort4 h, l;
  split_bf16(v.x, h.x, l.x);
  split_bf16(v.y, h.y, l.y);
  split_bf16(v.z, h.z, l.z);
  split_bf16(v.w, h.w, l.w);
  ((ushort4*)oh)[i] = h;
  ((ushort4*)ol)[i] = l;
}

// ---------------- W [H][K][D] fp32 -> Bt [H*D][K] bf16 hi/lo ----------------
__global__ __launch_bounds__(256) void convert_w(const float* __restrict__ W,
                                                 unsigned short* __restrict__ th,
                                                 unsigned short* __restrict__ tl,
                                                 int K, int D) {
  __shared__ float t[32][33];
  const int h = blockIdx.z;
  const int k0 = blockIdx.x * 32, d0 = blockIdx.y * 32;
  const int tx = threadIdx.x & 31, ty = threadIdx.x >> 5;
  const float* Wp = W + (size_t)h * K * D;
#pragma unroll
  for (int r = 0; r < 4; r++)
    t[ty + r * 8][tx] = Wp[(size_t)(k0 + ty + r * 8) * D + d0 + tx];
  __syncthreads();
#pragma unroll
  for (int r = 0; r < 4; r++) {
    int d = ty + r * 8;
    float v = t[tx][d];
    unsigned short hh, ll;
    split_bf16(v, hh, ll);
    size_t o = (size_t)(h * D + d0 + d) * K + k0 + tx;
    th[o] = hh;
    tl[o] = ll;
  }
}

// ---------------- split-bf16 MFMA GEMM ----------------
// C[M][Ntot] = A[M][K] @ Bt[Ntot][K]^T, A/B as bf16 hi/lo pairs.
// Block tile 128x64, BK=32, 256 threads (4 waves as 2x2), 16x16x32 MFMA.
// LDS tiles k-major: row r's 32 k-elements at [r*32 .. r*32+31] (4 x 16B chunks).
__global__ __launch_bounds__(256) void gemm_mfma(
    const unsigned short* __restrict__ Ah, const unsigned short* __restrict__ Al,
    const unsigned short* __restrict__ Bh, const unsigned short* __restrict__ Bl,
    float* __restrict__ C, int K, int Ntot) {
  __shared__ unsigned short lAh[BM * BK], lAl[BM * BK];
  __shared__ unsigned short lBh[BN * BK], lBl[BN * BK];

  const int tid = threadIdx.x;
  const int w = tid >> 6, lane = tid & 63;
  const int wm = w >> 1, wn = w & 1;
  const int quad = lane >> 4, l16 = lane & 15;
  const int m0 = blockIdx.x * BM, n0 = blockIdx.y * BN;

  // staging: chunk index c covers row c>>2, 16B-chunk c&3 (linear)
  const int cA0 = w * 128 + lane;        // A chunks 0..511 over 4 waves x 2
  const int cA1 = cA0 + 64;
  const int cB = w * 64 + lane;          // B chunks 0..255
  const unsigned short* gAh0 = Ah + (size_t)(m0 + (cA0 >> 2)) * K + (cA0 & 3) * 8;
  const unsigned short* gAh1 = Ah + (size_t)(m0 + (cA1 >> 2)) * K + (cA1 & 3) * 8;
  const unsigned short* gAl0 = Al + (size_t)(m0 + (cA0 >> 2)) * K + (cA0 & 3) * 8;
  const unsigned short* gAl1 = Al + (size_t)(m0 + (cA1 >> 2)) * K + (cA1 & 3) * 8;
  const unsigned short* gBh0 = Bh + (size_t)(n0 + (cB >> 2)) * K + (cB & 3) * 8;
  const unsigned short* gBl0 = Bl + (size_t)(n0 + (cB >> 2)) * K + (cB & 3) * 8;

  f32x4 acc[4][2];
#pragma unroll
  for (int i = 0; i < 4; i++)
#pragma unroll
    for (int j = 0; j < 2; j++) acc[i][j] = (f32x4){0.f, 0.f, 0.f, 0.f};

  for (int k0 = 0; k0 < K; k0 += BK) {
    GLL(gAh0 + k0, &lAh[cA0 * 8]);
    GLL(gAh1 + k0, &lAh[cA1 * 8]);
    GLL(gAl0 + k0, &lAl[cA0 * 8]);
    GLL(gAl1 + k0, &lAl[cA1 * 8]);
    GLL(gBh0 + k0, &lBh[cB * 8]);
    GLL(gBl0 + k0, &lBl[cB * 8]);
    __syncthreads();  // compiler drains vmcnt before barrier -> tiles visible

    // fragments: lane holds k = quad*8..quad*8+7 -> 16B chunk `quad` of its row
    bf16x8 fah[4], fal[4], fbh[2], fbl[2];
#pragma unroll
    for (int i = 0; i < 4; i++) {
      int off = (wm * 64 + i * 16 + l16) * 32 + quad * 8;
      fah[i] = *(const bf16x8*)&lAh[off];
      fal[i] = *(const bf16x8*)&lAl[off];
    }
#pragma unroll
    for (int j = 0; j < 2; j++) {
      int off = (wn * 32 + j * 16 + l16) * 32 + quad * 8;
      fbh[j] = *(const bf16x8*)&lBh[off];
      fbl[j] = *(const bf16x8*)&lBl[off];
    }
#pragma unroll
    for (int i = 0; i < 4; i++)
#pragma unroll
      for (int j = 0; j < 2; j++) {
        acc[i][j] = __builtin_amdgcn_mfma_f32_16x16x32_bf16(fah[i], fbh[j],
                                                            acc[i][j], 0, 0, 0);
        acc[i][j] = __builtin_amdgcn_mfma_f32_16x16x32_bf16(fah[i], fbl[j],
                                                            acc[i][j], 0, 0, 0);
        acc[i][j] = __builtin_amdgcn_mfma_f32_16x16x32_bf16(fal[i], fbh[j],
                                                            acc[i][j], 0, 0, 0);
      }
    __syncthreads();  // tiles consumed before next overwrite
  }

  // epilogue: C/D layout col = l16, row = quad*4 + reg
  const int gm = m0 + wm * 64 + quad * 4;
  const int gn = n0 + wn * 32 + l16;
#pragma unroll
  for (int i = 0; i < 4; i++)
#pragma unroll
    for (int j = 0; j < 2; j++) {
      float* p = C + (size_t)(gm + i * 16) * Ntot + gn + j * 16;
#pragma unroll
      for (int r = 0; r < 4; r++) p[(size_t)r * Ntot] = acc[i][j][r];
    }
}

// ---------------- f1/f2: per-node dots; Wh layout [n][h*D+d] ----------------
__global__ __launch_bounds__(256) void fvec(const float* __restrict__ Wh,
                                            const float* __restrict__ a,
                                            float* __restrict__ f1,
                                            float* __restrict__ f2, int H, int Dd,
                                            int HD) {
  __shared__ float buf[4];
  const int n = blockIdx.x;
  for (int h = 0; h < H; h++) {
    float s1 = 0.f, s2 = 0.f;
    for (int d = threadIdx.x; d < Dd; d += 256) {
      float v = Wh[(size_t)n * HD + h * Dd + d];
      s1 += v * a[(size_t)h * 2 * Dd + d];
      s2 += v * a[(size_t)h * 2 * Dd + Dd + d];
    }
    float t1 = block_sum(s1, buf);
    float t2 = block_sum(s2, buf);
    if (threadIdx.x == 0) {
      f1[h * N_NODES + n] = t1;
      f2[h * N_NODES + n] = t2;
    }
  }
}

// ---------------- layers 1&2: softmax-aggregate + elu(elu(.)) -> bf16 hi/lo ----------------
__global__ __launch_bounds__(256) void agg_concat(const float* __restrict__ Wh,
                                                  const float* __restrict__ f1,
                                                  const float* __restrict__ f2,
                                                  const int* __restrict__ cnt,
                                                  const int* __restrict__ idxs,
                                                  unsigned short* __restrict__ hh,
                                                  unsigned short* __restrict__ hl,
                                                  int H) {
  __shared__ int nbs[MAXNB];
  __shared__ float w[MAXNB];
  __shared__ float buf[4];
  const int n = blockIdx.x, tid = threadIdx.x;
  const int c = cnt[n];
  if (tid < c) nbs[tid] = idxs[n * MAXNB + tid];
  __syncthreads();
  for (int h = 0; h < H; h++) {
    float e = -3.0e38f;
    if (tid < c) {
      float s = f1[h * N_NODES + n] + f2[h * N_NODES + nbs[tid]];
      e = s >= 0.f ? s : 0.2f * s;  // leaky_relu
    }
    float m = block_max(e, buf);
    float wj = (tid < c) ? __expf(e - m) : 0.f;
    float tot = block_sum(wj, buf);
    if (tid < c) w[tid] = wj / tot;
    __syncthreads();
    float acc = 0.f;
    for (int jj = 0; jj < c; jj++)
      acc += w[jj] * Wh[(size_t)nbs[jj] * (H * 256) + h * 256 + tid];
    float v = acc;
    v = v > 0.f ? v : __expf(v) - 1.f;  // elu (per-head)
    v = v > 0.f ? v : __expf(v) - 1.f;  // elu (post-concat)
    unsigned short vh, vl;
    split_bf16(v, vh, vl);
    hh[(size_t)n * 1024 + h * 256 + tid] = vh;
    hl[(size_t)n * 1024 + h * 256 + tid] = vl;
    __syncthreads();
  }
}

// ---------------- layer 3: 6 heads mean + elu + L2-normalize ----------------
__global__ __launch_bounds__(256) void final_layer(const float* __restrict__ Wh,
                                                   const float* __restrict__ f1,
                                                   const float* __restrict__ f2,
                                                   const int* __restrict__ cnt,
                                                   const int* __restrict__ idxs,
                                                   float* __restrict__ out) {
  __shared__ int nbs[MAXNB];
  __shared__ float w[MAXNB];
  __shared__ float buf[4];
  const int n = blockIdx.x, tid = threadIdx.x;
  const int c = cnt[n];
  if (tid < c) nbs[tid] = idxs[n * MAXNB + tid];
  __syncthreads();
  float a0 = 0.f, a1 = 0.f;
  for (int h = 0; h < 6; h++) {
    float e = -3.0e38f;
    if (tid < c) {
      float s = f1[h * N_NODES + n] + f2[h * N_NODES + nbs[tid]];
      e = s >= 0.f ? s : 0.2f * s;
    }
    float m = block_max(e, buf);
    float wj = (tid < c) ? __expf(e - m) : 0.f;
    float tot = block_sum(wj, buf);
    if (tid < c) w[tid] = wj / tot;
    __syncthreads();
    for (int jj = 0; jj < c; jj++) {
      const float* row = Wh + (size_t)nbs[jj] * 3072 + h * 512;
      a0 += w[jj] * row[tid];
      a1 += w[jj] * row[tid + 256];
    }
    __syncthreads();
  }
  a0 *= (1.f / 6.f);
  a1 *= (1.f / 6.f);
  a0 = a0 > 0.f ? a0 : __expf(a0) - 1.f;
  a1 = a1 > 0.f ? a1 : __expf(a1) - 1.f;
  float ss = block_sum(a0 * a0 + a1 * a1, buf);
  float inv = 1.f / fmaxf(sqrtf(ss), 1e-12f);
  out[(size_t)n * 512 + tid] = a0 * inv;
  out[(size_t)n * 512 + 256 + tid] = a1 * inv;
}

extern "C" void kernel_launch(void* const* d_in, const int* in_sizes, int n_in,
                              void* d_out, int out_size, void* d_ws, size_t ws_size,
                              hipStream_t stream) {
  (void)in_sizes; (void)n_in; (void)out_size; (void)ws_size;
  const float* x   = (const float*)d_in[0];  // [4096, 2048]
  const float* adj = (const float*)d_in[1];  // [4096, 4096]
  const float* W1  = (const float*)d_in[2];  // [4, 2048, 256]
  const float* a1  = (const float*)d_in[3];  // [4, 512]
  const float* W2  = (const float*)d_in[4];  // [4, 1024, 256]
  const float* a2  = (const float*)d_in[5];  // [4, 512]
  const float* W3  = (const float*)d_in[6];  // [6, 1024, 512]
  const float* a3  = (const float*)d_in[7];  // [6, 1024]
  float* out = (float*)d_out;                // [4096, 512]

  // workspace layout (~82 MB)
  char* ws = (char*)d_ws;
  size_t off = 0;
  auto alloc = [&](size_t bytes) {
    void* p = ws + off;
    off += (bytes + 255) & ~(size_t)255;
    return p;
  };
  int* nbr_cnt = (int*)alloc((size_t)N_NODES * 4);
  int* nbr_idx = (int*)alloc((size_t)N_NODES * MAXNB * 4);
  float* f1 = (float*)alloc((size_t)6 * N_NODES * 4);
  float* f2 = (float*)alloc((size_t)6 * N_NODES * 4);
  unsigned short* Wt_h = (unsigned short*)alloc((size_t)6 * 1024 * 512 * 2);  // max: W3
  unsigned short* Wt_l = (unsigned short*)alloc((size_t)6 * 1024 * 512 * 2);
  unsigned short* hh = (unsigned short*)alloc((size_t)N_NODES * 1024 * 2);
  unsigned short* hl = (unsigned short*)alloc((size_t)N_NODES * 1024 * 2);
  float* Wh = (float*)alloc((size_t)N_NODES * 3072 * 4);  // 50.3 MB (L3); L1/L2 use first 16.8 MB
  // xh/xl live in the unused upper 2/3 of Wh during layer 1 (dead once L3 GEMM runs)
  unsigned short* xh = (unsigned short*)((char*)Wh + (size_t)N_NODES * 1024 * 4);
  unsigned short* xl = (unsigned short*)((char*)Wh + (size_t)N_NODES * 2048 * 4);

  build_csr<<<N_NODES, 256, 0, stream>>>(adj, nbr_cnt, nbr_idx);

  // ---- layer 1: A = x (K=2048), Ntot = 1024 ----
  convert_split<<<(N_NODES * 2048 / 4 + 255) / 256, 256, 0, stream>>>(x, xh, xl,
                                                                      N_NODES * 2048 / 4);
  convert_w<<<dim3(2048 / 32, 256 / 32, 4), 256, 0, stream>>>(W1, Wt_h, Wt_l, 2048, 256);
  gemm_mfma<<<dim3(N_NODES / BM, 1024 / BN), 256, 0, stream>>>(xh, xl, Wt_h, Wt_l,
                                                               Wh, 2048, 1024);
  fvec<<<N_NODES, 256, 0, stream>>>(Wh, a1, f1, f2, 4, 256, 1024);
  agg_concat<<<N_NODES, 256, 0, stream>>>(Wh, f1, f2, nbr_cnt, nbr_idx, hh, hl, 4);

  // ---- layer 2: A = h (K=1024), Ntot = 1024 ----
  convert_w<<<dim3(1024 / 32, 256 / 32, 4), 256, 0, stream>>>(W2, Wt_h, Wt_l, 1024, 256);
  gemm_mfma<<<dim3(N_NODES / BM, 1024 / BN), 256, 0, stream>>>(hh, hl, Wt_h, Wt_l,
                                                               Wh, 1024, 1024);
  fvec<<<N_NODES, 256, 0, stream>>>(Wh, a2, f1, f2, 4, 256, 1024);
  agg_concat<<<N_NODES, 256, 0, stream>>>(Wh, f1, f2, nbr_cnt, nbr_idx, hh, hl, 4);

  // ---- layer 3: A = h (K=1024), Ntot = 3072 ----
  convert_w<<<dim3(1024 / 32, 512 / 32, 6), 256, 0, stream>>>(W3, Wt_h, Wt_l, 1024, 512);
  gemm_mfma<<<dim3(N_NODES / BM, 3072 / BN), 256, 0, stream>>>(hh, hl, Wt_h, Wt_l,
                                                               Wh, 1024, 3072);
  fvec<<<N_NODES, 256, 0, stream>>>(Wh, a3, f1, f2, 6, 512, 3072);
  final_layer<<<N_NODES, 256, 0, stream>>>(Wh, f1, f2, nbr_cnt, nbr_idx, out);
}

// Round 4
// 577.258 us; speedup vs baseline: 2.1904x; 1.3620x over previous
//
#include <hip/hip_runtime.h>
#include <math.h>

// GAT, N=4096, ~1% adjacency. R4: Wh stored bf16-only (halves gather bytes);
// f1/f2 logits computed EXACTLY in the GEMM epilogue from fp32 accumulators
// (shfl-reduce + atomicAdd); fvec kernels deleted; one-pass wide-load aggregation.

#define N_NODES 4096
#define MAXNB 128
#define BM 128
#define BN 64
#define BK 32

typedef short bf16x8 __attribute__((ext_vector_type(8)));
typedef float f32x4 __attribute__((ext_vector_type(4)));

#define GLL(gp, lp)                                                     \
  __builtin_amdgcn_global_load_lds(                                     \
      (const __attribute__((address_space(1))) void*)(gp),              \
      (__attribute__((address_space(3))) void*)(lp), 16, 0, 0)

// ---------------- bf16 helpers ----------------
__device__ __forceinline__ unsigned short bf16_rne(float f) {
  unsigned int u = __float_as_uint(f);
  unsigned int r = (u + 0x7FFFu + ((u >> 16) & 1u)) >> 16;
  return (unsigned short)r;
}
__device__ __forceinline__ float bf2f(unsigned short v) {
  return __uint_as_float((unsigned int)v << 16);
}
__device__ __forceinline__ void split_bf16(float f, unsigned short& h,
                                           unsigned short& l) {
  h = bf16_rne(f);
  l = bf16_rne(f - bf2f(h));
}

// ---------------- reduction helpers (blockDim == 256) ----------------
__device__ __forceinline__ float wave_sum(float v) {
#pragma unroll
  for (int o = 32; o > 0; o >>= 1) v += __shfl_xor(v, o);
  return v;
}
__device__ __forceinline__ float wave_max(float v) {
#pragma unroll
  for (int o = 32; o > 0; o >>= 1) v = fmaxf(v, __shfl_xor(v, o));
  return v;
}
__device__ __forceinline__ float block_sum(float v, float* buf) {
  v = wave_sum(v);
  __syncthreads();
  if ((threadIdx.x & 63) == 0) buf[threadIdx.x >> 6] = v;
  __syncthreads();
  return buf[0] + buf[1] + buf[2] + buf[3];
}
__device__ __forceinline__ float block_max(float v, float* buf) {
  v = wave_max(v);
  __syncthreads();
  if ((threadIdx.x & 63) == 0) buf[threadIdx.x >> 6] = v;
  __syncthreads();
  return fmaxf(fmaxf(buf[0], buf[1]), fmaxf(buf[2], buf[3]));
}

// ---------------- zero f-buffers ----------------
__global__ __launch_bounds__(256) void zero_f(float* __restrict__ p, int n) {
  int i = blockIdx.x * 256 + threadIdx.x;
  if (i < n) p[i] = 0.f;
}

// ---------------- CSR build ----------------
__global__ __launch_bounds__(256) void build_csr(const float* __restrict__ adj,
                                                 int* __restrict__ cnt,
                                                 int* __restrict__ idx) {
  __shared__ int c;
  if (threadIdx.x == 0) c = 0;
  __syncthreads();
  const int row = blockIdx.x;
  const float* arow = adj + (size_t)row * N_NODES;
  for (int b = 0; b < N_NODES; b += 256) {
    float v = arow[b + threadIdx.x];
    if (v > 0.f) {
      int p = atomicAdd(&c, 1);
      if (p < MAXNB) idx[row * MAXNB + p] = b + threadIdx.x;
    }
  }
  __syncthreads();
  if (threadIdx.x == 0) cnt[row] = c < MAXNB ? c : MAXNB;
}

// ---------------- elementwise fp32 -> bf16 hi/lo ----------------
__global__ __launch_bounds__(256) void convert_split(const float* __restrict__ in,
                                                     unsigned short* __restrict__ oh,
                                                     unsigned short* __restrict__ ol,
                                                     int n4) {
  int i = blockIdx.x * 256 + threadIdx.x;
  if (i >= n4) return;
  float4 v = ((const float4*)in)[i];
  ushort4 h, l;
  split_bf16(v.x, h.x, l.x);
  split_bf16(v.y, h.y, l.y);
  split_bf16(v.z, h.z, l.z);
  split_bf16(v.w, h.w, l.w);
  ((ushort4*)oh)[i] = h;
  ((ushort4*)ol)[i] = l;
}

// ---------------- W [H][K][D] fp32 -> Bt [H*D][K] bf16 hi/lo ----------------
__global__ __launch_bounds__(256) void convert_w(const float* __restrict__ W,
                                                 unsigned short* __restrict__ th,
                                                 unsigned short* __restrict__ tl,
                                                 int K, int D) {
  __shared__ float t[32][33];
  const int h = blockIdx.z;
  const int k0 = blockIdx.x * 32, d0 = blockIdx.y * 32;
  const int tx = threadIdx.x & 31, ty = threadIdx.x >> 5;
  const float* Wp = W + (size_t)h * K * D;
#pragma unroll
  for (int r = 0; r < 4; r++)
    t[ty + r * 8][tx] = Wp[(size_t)(k0 + ty + r * 8) * D + d0 + tx];
  __syncthreads();
#pragma unroll
  for (int r = 0; r < 4; r++) {
    int d = ty + r * 8;
    float v = t[tx][d];
    unsigned short hh, ll;
    split_bf16(v, hh, ll);
    size_t o = (size_t)(h * D + d0 + d) * K + k0 + tx;
    th[o] = hh;
    tl[o] = ll;
  }
}

// ---------------- split-bf16 MFMA GEMM, bf16 output + fused f1/f2 ----------------
// Cb[M][Ntot] (bf16) = A[M][K] @ Bt[Ntot][K]^T; per-row dots with a-halves
// accumulated into f1/f2 (fp32, pre-zeroed) via shfl-reduce + atomicAdd.
// Block tile 128x64 (single head per block since 64 | D), BK=32, 4 waves (2x2).
__global__ __launch_bounds__(256) void gemm_mfma(
    const unsigned short* __restrict__ Ah, const unsigned short* __restrict__ Al,
    const unsigned short* __restrict__ Bh, const unsigned short* __restrict__ Bl,
    unsigned short* __restrict__ Cb, float* __restrict__ f1,
    float* __restrict__ f2, const float* __restrict__ af, int K, int Ntot, int D) {
  __shared__ unsigned short lAh[BM * BK], lAl[BM * BK];
  __shared__ unsigned short lBh[BN * BK], lBl[BN * BK];

  const int tid = threadIdx.x;
  const int w = tid >> 6, lane = tid & 63;
  const int wm = w >> 1, wn = w & 1;
  const int quad = lane >> 4, l16 = lane & 15;
  const int m0 = blockIdx.x * BM, n0 = blockIdx.y * BN;

  const int cA0 = w * 128 + lane;
  const int cA1 = cA0 + 64;
  const int cB = w * 64 + lane;
  const unsigned short* gAh0 = Ah + (size_t)(m0 + (cA0 >> 2)) * K + (cA0 & 3) * 8;
  const unsigned short* gAh1 = Ah + (size_t)(m0 + (cA1 >> 2)) * K + (cA1 & 3) * 8;
  const unsigned short* gAl0 = Al + (size_t)(m0 + (cA0 >> 2)) * K + (cA0 & 3) * 8;
  const unsigned short* gAl1 = Al + (size_t)(m0 + (cA1 >> 2)) * K + (cA1 & 3) * 8;
  const unsigned short* gBh0 = Bh + (size_t)(n0 + (cB >> 2)) * K + (cB & 3) * 8;
  const unsigned short* gBl0 = Bl + (size_t)(n0 + (cB >> 2)) * K + (cB & 3) * 8;

  f32x4 acc[4][2];
#pragma unroll
  for (int i = 0; i < 4; i++)
#pragma unroll
    for (int j = 0; j < 2; j++) acc[i][j] = (f32x4){0.f, 0.f, 0.f, 0.f};

  for (int k0 = 0; k0 < K; k0 += BK) {
    GLL(gAh0 + k0, &lAh[cA0 * 8]);
    GLL(gAh1 + k0, &lAh[cA1 * 8]);
    GLL(gAl0 + k0, &lAl[cA0 * 8]);
    GLL(gAl1 + k0, &lAl[cA1 * 8]);
    GLL(gBh0 + k0, &lBh[cB * 8]);
    GLL(gBl0 + k0, &lBl[cB * 8]);
    __syncthreads();

    bf16x8 fah[4], fal[4], fbh[2], fbl[2];
#pragma unroll
    for (int i = 0; i < 4; i++) {
      int off = (wm * 64 + i * 16 + l16) * 32 + quad * 8;
      fah[i] = *(const bf16x8*)&lAh[off];
      fal[i] = *(const bf16x8*)&lAl[off];
    }
#pragma unroll
    for (int j = 0; j < 2; j++) {
      int off = (wn * 32 + j * 16 + l16) * 32 + quad * 8;
      fbh[j] = *(const bf16x8*)&lBh[off];
      fbl[j] = *(const bf16x8*)&lBl[off];
    }
#pragma unroll
    for (int i = 0; i < 4; i++)
#pragma unroll
      for (int j = 0; j < 2; j++) {
        acc[i][j] = __builtin_amdgcn_mfma_f32_16x16x32_bf16(fah[i], fbh[j],
                                                            acc[i][j], 0, 0, 0);
        acc[i][j] = __builtin_amdgcn_mfma_f32_16x16x32_bf16(fah[i], fbl[j],
                                                            acc[i][j], 0, 0, 0);
        acc[i][j] = __builtin_amdgcn_mfma_f32_16x16x32_bf16(fal[i], fbh[j],
                                                            acc[i][j], 0, 0, 0);
      }
    __syncthreads();
  }

  // ---- epilogue 1: bf16 C write (C/D layout: col=l16, row=quad*4+r) ----
  const int gm = m0 + wm * 64 + quad * 4;
  const int gn = n0 + wn * 32 + l16;
#pragma unroll
  for (int i = 0; i < 4; i++)
#pragma unroll
    for (int j = 0; j < 2; j++) {
      unsigned short* p = Cb + (size_t)(gm + i * 16) * Ntot + gn + j * 16;
#pragma unroll
      for (int r = 0; r < 4; r++) p[(size_t)r * Ntot] = bf16_rne(acc[i][j][r]);
    }

  // ---- epilogue 2: exact f1/f2 from fp32 acc ----
  const int h = n0 / D;
  const int d0 = (n0 % D) + wn * 32 + l16;  // j=0 column's d; j=1 is d0+16
  const float a10 = af[h * 2 * D + d0];
  const float a11 = af[h * 2 * D + d0 + 16];
  const float a20 = af[h * 2 * D + D + d0];
  const float a21 = af[h * 2 * D + D + d0 + 16];
#pragma unroll
  for (int i = 0; i < 4; i++)
#pragma unroll
    for (int r = 0; r < 4; r++) {
      float s1 = acc[i][0][r] * a10 + acc[i][1][r] * a11;
      float s2 = acc[i][0][r] * a20 + acc[i][1][r] * a21;
#pragma unroll
      for (int m = 1; m < 16; m <<= 1) {
        s1 += __shfl_xor(s1, m);
        s2 += __shfl_xor(s2, m);
      }
      if (l16 == 0) {
        int row = gm + i * 16 + r;  // gm already includes quad*4
        atomicAdd(&f1[h * N_NODES + row], s1);
        atomicAdd(&f2[h * N_NODES + row], s2);
      }
    }
}

// ---------------- layers 1&2: one-pass aggregate (H=4, row=1024 bf16) ----------------
__global__ __launch_bounds__(256) void agg4(const unsigned short* __restrict__ Whb,
                                            const float* __restrict__ f1,
                                            const float* __restrict__ f2,
                                            const int* __restrict__ cnt,
                                            const int* __restrict__ idxs,
                                            unsigned short* __restrict__ hh,
                                            unsigned short* __restrict__ hl) {
  __shared__ int nbs[MAXNB];
  __shared__ float wgt[4][MAXNB];
  __shared__ float buf[4];
  const int n = blockIdx.x, tid = threadIdx.x;
  const int c = cnt[n];
  if (tid < c) nbs[tid] = idxs[n * MAXNB + tid];
  __syncthreads();
  for (int h = 0; h < 4; h++) {
    float e = -3.0e38f;
    if (tid < c) {
      float s = f1[h * N_NODES + n] + f2[h * N_NODES + nbs[tid]];
      e = s >= 0.f ? s : 0.2f * s;  // leaky_relu
    }
    float m = block_max(e, buf);
    float wj = (tid < c) ? __expf(e - m) : 0.f;
    float tot = block_sum(wj, buf);
    if (tid < c) wgt[h][tid] = wj / tot;
  }
  __syncthreads();
  // each thread owns 4 consecutive columns of the 1024-wide row (one head)
  const int c0 = tid * 4;
  const int hd = c0 >> 8;
  float ax = 0.f, ay = 0.f, az = 0.f, aw = 0.f;
  for (int jj = 0; jj < c; jj++) {
    ushort4 v = *(const ushort4*)(Whb + (size_t)nbs[jj] * 1024 + c0);
    float wv = wgt[hd][jj];
    ax += wv * bf2f(v.x);
    ay += wv * bf2f(v.y);
    az += wv * bf2f(v.z);
    aw += wv * bf2f(v.w);
  }
  float o[4] = {ax, ay, az, aw};
  ushort4 oh, ol;
  unsigned short* ph = (unsigned short*)&oh;
  unsigned short* pl = (unsigned short*)&ol;
#pragma unroll
  for (int s = 0; s < 4; s++) {
    float v = o[s];
    v = v > 0.f ? v : __expf(v) - 1.f;  // elu (per-head)
    v = v > 0.f ? v : __expf(v) - 1.f;  // elu (post-concat)
    split_bf16(v, ph[s], pl[s]);
  }
  *(ushort4*)(hh + (size_t)n * 1024 + c0) = oh;
  *(ushort4*)(hl + (size_t)n * 1024 + c0) = ol;
}

// ---------------- layer 3: one-pass aggregate (H=6, row=3072 bf16) + mean/elu/norm ----------------
__global__ __launch_bounds__(256) void final6(const unsigned short* __restrict__ Whb,
                                              const float* __restrict__ f1,
                                              const float* __restrict__ f2,
                                              const int* __restrict__ cnt,
                                              const int* __restrict__ idxs,
                                              float* __restrict__ out) {
  __shared__ int nbs[MAXNB];
  __shared__ float wgt[6][MAXNB];
  __shared__ float buf[4];
  __shared__ float sAgg[3072];
  const int n = blockIdx.x, tid = threadIdx.x;
  const int c = cnt[n];
  if (tid < c) nbs[tid] = idxs[n * MAXNB + tid];
  __syncthreads();
  for (int h = 0; h < 6; h++) {
    float e = -3.0e38f;
    if (tid < c) {
      float s = f1[h * N_NODES + n] + f2[h * N_NODES + nbs[tid]];
      e = s >= 0.f ? s : 0.2f * s;
    }
    float m = block_max(e, buf);
    float wj = (tid < c) ? __expf(e - m) : 0.f;
    float tot = block_sum(wj, buf);
    if (tid < c) wgt[h][tid] = (wj / tot) * (1.f / 6.f);  // fold head-mean
  }
  __syncthreads();
  // each thread owns 12 consecutive columns (3 quads; each quad within one head)
  const int c0 = tid * 12;
  const int h0 = (c0) >> 9, h1 = (c0 + 4) >> 9, h2 = (c0 + 8) >> 9;
  float acc[12];
#pragma unroll
  for (int s = 0; s < 12; s++) acc[s] = 0.f;
  for (int jj = 0; jj < c; jj++) {
    const unsigned short* row = Whb + (size_t)nbs[jj] * 3072 + c0;
    ushort4 v0 = *(const ushort4*)(row);
    ushort4 v1 = *(const ushort4*)(row + 4);
    ushort4 v2 = *(const ushort4*)(row + 8);
    float w0 = wgt[h0][jj], w1 = wgt[h1][jj], w2 = wgt[h2][jj];
    acc[0] += w0 * bf2f(v0.x); acc[1] += w0 * bf2f(v0.y);
    acc[2] += w0 * bf2f(v0.z); acc[3] += w0 * bf2f(v0.w);
    acc[4] += w1 * bf2f(v1.x); acc[5] += w1 * bf2f(v1.y);
    acc[6] += w1 * bf2f(v1.z); acc[7] += w1 * bf2f(v1.w);
    acc[8] += w2 * bf2f(v2.x); acc[9] += w2 * bf2f(v2.y);
    acc[10] += w2 * bf2f(v2.z); acc[11] += w2 * bf2f(v2.w);
  }
#pragma unroll
  for (int s = 0; s < 12; s++) sAgg[c0 + s] = acc[s];
  __syncthreads();
  // out[d] = elu(sum_h sAgg[h*512+d]) (mean already folded), then L2-normalize
  float v0 = 0.f, v1 = 0.f;
#pragma unroll
  for (int h = 0; h < 6; h++) {
    v0 += sAgg[h * 512 + tid];
    v1 += sAgg[h * 512 + tid + 256];
  }
  v0 = v0 > 0.f ? v0 : __expf(v0) - 1.f;
  v1 = v1 > 0.f ? v1 : __expf(v1) - 1.f;
  float ss = block_sum(v0 * v0 + v1 * v1, buf);
  float inv = 1.f / fmaxf(sqrtf(ss), 1e-12f);
  out[(size_t)n * 512 + tid] = v0 * inv;
  out[(size_t)n * 512 + 256 + tid] = v1 * inv;
}

extern "C" void kernel_launch(void* const* d_in, const int* in_sizes, int n_in,
                              void* d_out, int out_size, void* d_ws, size_t ws_size,
                              hipStream_t stream) {
  (void)in_sizes; (void)n_in; (void)out_size; (void)ws_size;
  const float* x   = (const float*)d_in[0];  // [4096, 2048]
  const float* adj = (const float*)d_in[1];  // [4096, 4096]
  const float* W1  = (const float*)d_in[2];  // [4, 2048, 256]
  const float* a1  = (const float*)d_in[3];  // [4, 512]
  const float* W2  = (const float*)d_in[4];  // [4, 1024, 256]
  const float* a2  = (const float*)d_in[5];  // [4, 512]
  const float* W3  = (const float*)d_in[6];  // [6, 1024, 512]
  const float* a3  = (const float*)d_in[7];  // [6, 1024]
  float* out = (float*)d_out;                // [4096, 512]

  // workspace layout (~74 MB peak)
  char* ws = (char*)d_ws;
  size_t off = 0;
  auto alloc = [&](size_t bytes) {
    void* p = ws + off;
    off += (bytes + 255) & ~(size_t)255;
    return p;
  };
  int* nbr_cnt = (int*)alloc((size_t)N_NODES * 4);
  int* nbr_idx = (int*)alloc((size_t)N_NODES * MAXNB * 4);
  float* fbuf = (float*)alloc((size_t)28 * N_NODES * 4);  // f1/f2 per layer, zeroed
  unsigned short* Wt_h = (unsigned short*)alloc((size_t)6 * 1024 * 512 * 2);
  unsigned short* Wt_l = (unsigned short*)alloc((size_t)6 * 1024 * 512 * 2);
  // R region (33.6 MB): xh/xl during layer-1 GEMM, then hh/hl (xh dead after GEMM1)
  unsigned short* R = (unsigned short*)alloc((size_t)N_NODES * 2048 * 2 * 2);
  unsigned short* xh = R;
  unsigned short* xl = R + (size_t)N_NODES * 2048;
  unsigned short* hh = R;
  unsigned short* hl = R + (size_t)N_NODES * 1024;
  unsigned short* Whb = (unsigned short*)alloc((size_t)N_NODES * 3072 * 2);  // bf16, max L3

  float* f1_1 = fbuf;                 // 4 heads
  float* f2_1 = fbuf + 4 * N_NODES;
  float* f1_2 = fbuf + 8 * N_NODES;   // 4 heads
  float* f2_2 = fbuf + 12 * N_NODES;
  float* f1_3 = fbuf + 16 * N_NODES;  // 6 heads
  float* f2_3 = fbuf + 22 * N_NODES;

  zero_f<<<(28 * N_NODES + 255) / 256, 256, 0, stream>>>(fbuf, 28 * N_NODES);
  build_csr<<<N_NODES, 256, 0, stream>>>(adj, nbr_cnt, nbr_idx);

  // ---- layer 1: A = x (K=2048), Ntot = 1024, D = 256 ----
  convert_split<<<(N_NODES * 2048 / 4 + 255) / 256, 256, 0, stream>>>(
      x, xh, xl, N_NODES * 2048 / 4);
  convert_w<<<dim3(2048 / 32, 256 / 32, 4), 256, 0, stream>>>(W1, Wt_h, Wt_l, 2048, 256);
  gemm_mfma<<<dim3(N_NODES / BM, 1024 / BN), 256, 0, stream>>>(
      xh, xl, Wt_h, Wt_l, Whb, f1_1, f2_1, a1, 2048, 1024, 256);
  agg4<<<N_NODES, 256, 0, stream>>>(Whb, f1_1, f2_1, nbr_cnt, nbr_idx, hh, hl);

  // ---- layer 2: A = h (K=1024), Ntot = 1024, D = 256 ----
  convert_w<<<dim3(1024 / 32, 256 / 32, 4), 256, 0, stream>>>(W2, Wt_h, Wt_l, 1024, 256);
  gemm_mfma<<<dim3(N_NODES / BM, 1024 / BN), 256, 0, stream>>>(
      hh, hl, Wt_h, Wt_l, Whb, f1_2, f2_2, a2, 1024, 1024, 256);
  agg4<<<N_NODES, 256, 0, stream>>>(Whb, f1_2, f2_2, nbr_cnt, nbr_idx, hh, hl);

  // ---- layer 3: A = h (K=1024), Ntot = 3072, D = 512 ----
  convert_w<<<dim3(1024 / 32, 512 / 32, 6), 256, 0, stream>>>(W3, Wt_h, Wt_l, 1024, 512);
  gemm_mfma<<<dim3(N_NODES / BM, 3072 / BN), 256, 0, stream>>>(
      hh, hl, Wt_h, Wt_l, Whb, f1_3, f2_3, a3, 1024, 3072, 512);
  final6<<<N_NODES, 256, 0, stream>>>(Whb, f1_3, f2_3, nbr_cnt, nbr_idx, out);
}